// Round 10
// 626.217 us; speedup vs baseline: 1.6744x; 1.1274x over previous
//
#include <hip/hip_runtime.h>
#include <math.h>

// Problem dims
#define B_   8
#define T_   64
#define N_   200
#define CIN_ 200
#define C_   128
#define L_   2
#define NC_  2
#define S_   100
#define BT_  512      // B*T
#define RB_  102400   // B*T*N

typedef __attribute__((ext_vector_type(8))) short short8v;
typedef __attribute__((ext_vector_type(4))) float f32x4v;

union U4S8 { uint4 u; short8v s; };

__device__ __forceinline__ unsigned short f2bf(float f) {
    unsigned u = __float_as_uint(f);
    unsigned r = (u + 0x7FFFu + ((u >> 16) & 1u)) >> 16;   // RNE
    return (unsigned short)r;
}
__device__ __forceinline__ float bf2f(unsigned short u) {
    return __uint_as_float(((unsigned)u) << 16);
}
__device__ __forceinline__ float bflo(unsigned u) { return __uint_as_float(u << 16); }
__device__ __forceinline__ float bfhi(unsigned u) { return __uint_as_float(u & 0xFFFF0000u); }
__device__ __forceinline__ unsigned packbf(float a, float b) {
    return (unsigned)f2bf(a) | ((unsigned)f2bf(b) << 16);
}

#define GLL(src, dst) __builtin_amdgcn_global_load_lds( \
    (const __attribute__((address_space(1))) unsigned int*)(src), \
    (__attribute__((address_space(3))) unsigned int*)(dst), 16, 0, 0)

// ============================================================================
// thr_kernel v5: SINGLE global pass (unchanged).
__global__ __launch_bounds__(1024) void thr_kernel(const float* __restrict__ a,
                                                   float* __restrict__ thr,
                                                   unsigned* __restrict__ msk) {
    __shared__ int      hist[1024];
    __shared__ int      red[1024];
    __shared__ unsigned smask[1400];
    __shared__ float    candV[6144];
    __shared__ unsigned short candP[6144];
    __shared__ int      part[256];
    __shared__ int      grp[32];
    __shared__ float    cand2[256];
    __shared__ int      meta[8];
    __shared__ float    s_thr;
    int tid = threadIdx.x, lane = tid & 63;
    int bt = blockIdx.x;
    hist[tid] = 0;
    for (int i = tid; i < 1400; i += 1024) smask[i] = 0u;
    if (tid == 0) { meta[0] = 0; meta[1] = 0; }
    __syncthreads();

    const float4* x4 = (const float4*)(a + (long)bt * 40000);
    int c_lo = 0;
    #pragma unroll 1
    for (int it = 0; it < 10; it++) {
        int i4 = tid + it * 1024;
        unsigned nhi = 0u, ncm = 0u;
        float vv[4] = {0.f, 0.f, 0.f, 0.f};
        if (i4 < 10000) {
            float4 v = x4[i4];
            vv[0] = v.x; vv[1] = v.y; vv[2] = v.z; vv[3] = v.w;
            #pragma unroll
            for (int j = 0; j < 4; j++) {
                float f = vv[j];
                if (f < 0.65f) c_lo++;
                else if (f < 0.75f) ncm |= 1u << j;
                else nhi |= 1u << j;
            }
            if (nhi) {
                int vi = i4 * 4;
                int row = vi / 200, col = vi - row * 200;
                atomicOr(&smask[row * 7 + (col >> 5)], nhi << (col & 31));
            }
        }
        int cnt = __popc(ncm);
        int pfx = cnt;
        #pragma unroll
        for (int d = 1; d < 64; d <<= 1) {
            int t = __shfl_up(pfx, d, 64);
            if (lane >= d) pfx += t;
        }
        int total = __shfl(pfx, 63, 64);
        if (total) {
            int bw = 0;
            if (lane == 63) bw = atomicAdd(&meta[0], total);
            bw = __shfl(bw, 63, 64);
            int p = bw + pfx - cnt;
            #pragma unroll
            for (int j = 0; j < 4; j++) {
                if ((ncm >> j) & 1u) {
                    float f = vv[j];
                    if (p < 6144) { candV[p] = f; candP[p] = (unsigned short)(i4 * 4 + j); }
                    int bin = (int)((f - 0.65f) * 10240.0f);
                    bin = bin < 0 ? 0 : (bin > 1023 ? 1023 : bin);
                    atomicAdd(&hist[bin], 1);
                    p++;
                }
            }
        }
    }
    red[tid] = c_lo;
    __syncthreads();
    for (int off = 512; off; off >>= 1) {
        if (tid < off) red[tid] += red[tid + off];
        __syncthreads();
    }
    int c_lo_tot = red[0];
    if (tid < 256) part[tid] = hist[4*tid] + hist[4*tid+1] + hist[4*tid+2] + hist[4*tid+3];
    __syncthreads();
    if (tid < 32) {
        int s = 0;
        for (int i = 0; i < 8; i++) s += part[8*tid + i];
        grp[tid] = s;
    }
    __syncthreads();
    if (tid == 0) {
        int r = 27999 - c_lo_tot;
        int cum = 0, g = 0;
        while (cum + grp[g] <= r) cum += grp[g++];
        int t = g * 8;
        while (cum + part[t] <= r) cum += part[t++];
        int b = t * 4;
        while (cum + hist[b] <= r) cum += hist[b++];
        meta[2] = b; meta[3] = cum;
        int r1 = r + 1;
        cum = 0; g = 0;
        while (cum + grp[g] <= r1) cum += grp[g++];
        t = g * 8;
        while (cum + part[t] <= r1) cum += part[t++];
        b = t * 4;
        while (cum + hist[b] <= r1) cum += hist[b++];
        meta[4] = b; meta[5] = r;
    }
    __syncthreads();
    int blo = meta[2], base = meta[3], bhi = meta[4], r = meta[5];
    int m = meta[0]; if (m > 6144) m = 6144;
    for (int i = tid; i < m; i += 1024) {
        float v = candV[i];
        int bin = (int)((v - 0.65f) * 10240.0f);
        bin = bin < 0 ? 0 : (bin > 1023 ? 1023 : bin);
        if (bin >= blo && bin <= bhi) {
            int p = atomicAdd(&meta[1], 1);
            if (p < 256) cand2[p] = v;
        }
    }
    __syncthreads();
    if (tid == 0) {
        int m2 = meta[1]; if (m2 > 256) m2 = 256;
        for (int i = 1; i < m2; i++) {
            float key = cand2[i]; int j = i - 1;
            while (j >= 0 && cand2[j] > key) { cand2[j+1] = cand2[j]; j--; }
            cand2[j+1] = key;
        }
        float s1 = cand2[r - base], s2 = cand2[r + 1 - base];
        float tv = s1 * 0.701171875f + s2 * 0.298828125f;
        thr[bt] = tv;
        s_thr = tv;
    }
    __syncthreads();
    float tv = s_thr;
    for (int i = tid; i < m; i += 1024) {
        if (candV[i] > tv) {
            int vi = candP[i];
            int row = vi / 200, col = vi - row * 200;
            atomicOr(&smask[row * 7 + (col >> 5)], 1u << (col & 31));
        }
    }
    __syncthreads();
    for (int i = tid; i < 1400; i += 1024)
        msk[(long)bt * 1400 + i] = smask[i];
}

// ============================================================================
// wtcvt5: all 5 weight transposes in ONE dispatch (640 blocks x 64 threads)
__global__ void wtcvt5_kernel(const float* __restrict__ w_init,
                              const float* __restrict__ gin_w1,
                              const float* __restrict__ gin_w2,
                              unsigned short* __restrict__ WT0,
                              unsigned short* __restrict__ WT1,
                              unsigned short* __restrict__ WT2) {
    int grp = blockIdx.x >> 7, c = blockIdx.x & 127;
    const float* w; unsigned short* wt; int K, Kpad;
    if (grp == 0)      { w = w_init;                     wt = WT0;                     K = 200; Kpad = 224; }
    else if (grp <= 2) { w = gin_w1 + (grp - 1) * C_ * C_; wt = WT1 + (grp - 1) * 128 * 128; K = 128; Kpad = 128; }
    else               { w = gin_w2 + (grp - 3) * C_ * C_; wt = WT2 + (grp - 3) * 128 * 128; K = 128; Kpad = 128; }
    for (int k = threadIdx.x; k < Kpad; k += 64)
        wt[(long)c * Kpad + k] = f2bf((k < K) ? w[(long)k * 128 + c] : 0.f);
}

// ============================================================================
// bngemm v3 (stage-all): Y1raw = relu(bn1(y2)) @ w2 + b2, fused BN2 stats.
__global__ __launch_bounds__(256) void bngemm_kernel(
        const unsigned short* __restrict__ xb,
        const unsigned short* __restrict__ wt,
        const float* __restrict__ bias, const float* __restrict__ statsIn,
        const float* __restrict__ bng, const float* __restrict__ bnb,
        unsigned short* __restrict__ y, float* __restrict__ statsOut) {
    __shared__ unsigned char pool[65536];
    __shared__ float bnS[128], bnB[128];
    int tid = threadIdx.x;
    int wave = tid >> 6, lane = tid & 63, quad = lane >> 4, m16 = lane & 15;
    long row0g = (long)blockIdx.x * 128;

    {
        int r0 = tid >> 2;
        int csw = (tid & 3) ^ ((r0 >> 1) & 3);
        int r1 = 64 + (tid >> 2);
        int csw1 = (tid & 3) ^ ((r1 >> 1) & 3);
        #pragma unroll
        for (int ks = 0; ks < 4; ks++) {
            char* Adst = (char*)pool + ks * 16384;
            char* Bdst = Adst + 8192;
            GLL((const char*)xb + ((row0g + r0) * 128 + ks * 32) * 2 + csw * 16,
                Adst + wave * 1024);
            GLL((const char*)xb + ((row0g + r1) * 128 + ks * 32) * 2 + csw1 * 16,
                Adst + 4096 + wave * 1024);
            GLL((const char*)wt + (long)r0 * 256 + ks * 64 + csw * 16,
                Bdst + wave * 1024);
            GLL((const char*)wt + (long)r1 * 256 + ks * 64 + csw1 * 16,
                Bdst + 4096 + wave * 1024);
        }
    }
    if (tid < 128) {
        float mm = statsIn[tid] * (1.f / (float)RB_);
        float var = fmaxf(statsIn[128 + tid] * (1.f / (float)RB_) - mm * mm, 0.f);
        float sc = bng[tid] / sqrtf(var + 1e-5f);
        bnS[tid] = sc; bnB[tid] = bnb[tid] - mm * sc;
    }
    f32x4v acc[2][8];
    #pragma unroll
    for (int i = 0; i < 2; i++)
        #pragma unroll
        for (int j = 0; j < 8; j++) acc[i][j] = (f32x4v){0.f, 0.f, 0.f, 0.f};

    __syncthreads();

    #pragma unroll 1
    for (int ks = 0; ks < 4; ks++) {
        const char* Ab = (const char*)pool + ks * 16384;
        const char* Bb = Ab + 8192;
        int kf = ks * 32 + quad * 8;
        U4S8 bU[8];
        #pragma unroll
        for (int nt = 0; nt < 8; nt++) {
            int r = nt * 16 + m16;
            int ch = quad ^ ((r >> 1) & 3);
            bU[nt].u = *(const uint4*)(Bb + r * 64 + ch * 16);
        }
        U4S8 aU[2];
        #pragma unroll
        for (int mt = 0; mt < 2; mt++) {
            int r = wave * 32 + mt * 16 + m16;
            int ch = quad ^ ((r >> 1) & 3);
            aU[mt].u = *(const uint4*)(Ab + r * 64 + ch * 16);
        }
        float4 s0 = *(const float4*)&bnS[kf], s1 = *(const float4*)&bnS[kf + 4];
        float4 b0 = *(const float4*)&bnB[kf], b1 = *(const float4*)&bnB[kf + 4];
        #pragma unroll
        for (int mt = 0; mt < 2; mt++) {
            uint4 u = aU[mt].u;
            float f0 = fmaxf(bflo(u.x) * s0.x + b0.x, 0.f);
            float f1 = fmaxf(bfhi(u.x) * s0.y + b0.y, 0.f);
            float f2 = fmaxf(bflo(u.y) * s0.z + b0.z, 0.f);
            float f3 = fmaxf(bfhi(u.y) * s0.w + b0.w, 0.f);
            float f4 = fmaxf(bflo(u.z) * s1.x + b1.x, 0.f);
            float f5 = fmaxf(bfhi(u.z) * s1.y + b1.y, 0.f);
            float f6 = fmaxf(bflo(u.w) * s1.z + b1.z, 0.f);
            float f7 = fmaxf(bfhi(u.w) * s1.w + b1.w, 0.f);
            u.x = packbf(f0, f1); u.y = packbf(f2, f3);
            u.z = packbf(f4, f5); u.w = packbf(f6, f7);
            aU[mt].u = u;
        }
        #pragma unroll
        for (int nt = 0; nt < 8; nt++) {
            acc[0][nt] = __builtin_amdgcn_mfma_f32_16x16x32_bf16(aU[0].s, bU[nt].s, acc[0][nt], 0, 0, 0);
            acc[1][nt] = __builtin_amdgcn_mfma_f32_16x16x32_bf16(aU[1].s, bU[nt].s, acc[1][nt], 0, 0, 0);
        }
    }

    __syncthreads();
    unsigned short* trans = (unsigned short*)pool;
    float sAcc[8], qAcc[8];
    #pragma unroll
    for (int nt = 0; nt < 8; nt++) {
        int col = nt * 16 + m16;
        float bv = bias[col];
        float s = 0.f, q = 0.f;
        #pragma unroll
        for (int mt = 0; mt < 2; mt++) {
            int lrb = wave * 32 + mt * 16 + quad * 4;
            #pragma unroll
            for (int i = 0; i < 4; i++) {
                int lr = lrb + i;
                float v = acc[mt][nt][i] + bv;
                trans[lr * 128 + (col ^ ((lr & 6) << 2))] = f2bf(v);
                s += v; q += v * v;
            }
        }
        sAcc[nt] = s; qAcc[nt] = q;
    }
    __syncthreads();
    #pragma unroll
    for (int rnd = 0; rnd < 8; rnd++) {
        int row = rnd * 16 + (tid >> 4), ch = tid & 15;
        uint4 v = *(const uint4*)&trans[row * 128 + ((ch * 8) ^ ((row & 6) << 2))];
        *(uint4*)&y[(row0g + row) * 128 + ch * 8] = v;
    }
    __syncthreads();
    float* redS = (float*)pool;
    float* redQ = redS + 2048;
    #pragma unroll
    for (int nt = 0; nt < 8; nt++) {
        int col = nt * 16 + m16;
        redS[col * 16 + wave * 4 + quad] = sAcc[nt];
        redQ[col * 16 + wave * 4 + quad] = qAcc[nt];
    }
    __syncthreads();
    if (tid < 128) {
        float s = 0.f, q = 0.f;
        #pragma unroll
        for (int j = 0; j < 16; j++) { s += redS[tid * 16 + j]; q += redQ[tid * 16 + j]; }
        atomicAdd(&statsOut[tid], s);
        atomicAdd(&statsOut[128 + tid], q);
    }
}

// ============================================================================
// h3gemmT: h3 = fv @ w_init + b_init, dual output (row + transposed). Unchanged.
__global__ __launch_bounds__(256) void h3gemmT_kernel(
        const float* __restrict__ xv, const unsigned short* __restrict__ wt,
        const float* __restrict__ bias,
        unsigned short* __restrict__ yrow, unsigned short* __restrict__ zt) {
    __shared__ unsigned char pool[49152];
    int tid = threadIdx.x;
    int wave = tid >> 6, lane = tid & 63, quad = lane >> 4, m16 = lane & 15;
    long row0g = (long)blockIdx.x * 128;

    auto STAGE = [&](int buf, int ks) {
        #pragma unroll
        for (int j = 0; j < 2; j++) {
            int r = j * 64 + (tid >> 2);
            int c = (tid & 3) ^ ((r >> 1) & 3);
            const char* src = (const char*)wt + (long)r * 448 + ks * 64 + c * 16;
            char* dst = (char*)pool + 32768 + buf * 8192 + j * 4096 + wave * 1024;
            GLL(src, dst);
        }
        const char* xb = (const char*)xv;
        #pragma unroll
        for (int j = 0; j < 4; j++) {
            int r = j * 32 + (tid >> 3);
            int c = (tid & 7) ^ (r & 7);
            const char* src = xb + ((row0g + r) * 200 + ks * 32) * 4 + c * 16;
            char* dst = (char*)pool + buf * 16384 + j * 4096 + wave * 1024;
            GLL(src, dst);
        }
    };

    f32x4v acc[2][8];
    #pragma unroll
    for (int i = 0; i < 2; i++)
        #pragma unroll
        for (int j = 0; j < 8; j++) acc[i][j] = (f32x4v){0.f, 0.f, 0.f, 0.f};

    STAGE(0, 0);
    __syncthreads();

    for (int ks = 0; ks < 6; ks++) {
        if (ks + 1 < 6) {
            STAGE((ks + 1) & 1, ks + 1);
            asm volatile("s_waitcnt vmcnt(6)" ::: "memory");
        } else {
            asm volatile("s_waitcnt vmcnt(0)" ::: "memory");
        }
        __builtin_amdgcn_s_barrier();
        asm volatile("" ::: "memory");

        const char* Ab = (const char*)pool + (ks & 1) * 16384;
        const char* Bb = (const char*)pool + 32768 + (ks & 1) * 8192;
        U4S8 bU[8];
        #pragma unroll
        for (int nt = 0; nt < 8; nt++) {
            int r = nt * 16 + m16;
            int ch = quad ^ ((r >> 1) & 3);
            bU[nt].u = *(const uint4*)(Bb + r * 64 + ch * 16);
        }
        U4S8 aU[2];
        #pragma unroll
        for (int mt = 0; mt < 2; mt++) {
            int r = wave * 32 + mt * 16 + m16;
            int swz = r & 7;
            const char* base = Ab + r * 128;
            float4 v0 = *(const float4*)(base + ((2 * quad) ^ swz) * 16);
            float4 v1 = *(const float4*)(base + ((2 * quad + 1) ^ swz) * 16);
            uint4 o;
            o.x = packbf(v0.x, v0.y); o.y = packbf(v0.z, v0.w);
            o.z = packbf(v1.x, v1.y); o.w = packbf(v1.z, v1.w);
            aU[mt].u = o;
        }
        #pragma unroll
        for (int nt = 0; nt < 8; nt++) {
            acc[0][nt] = __builtin_amdgcn_mfma_f32_16x16x32_bf16(aU[0].s, bU[nt].s, acc[0][nt], 0, 0, 0);
            acc[1][nt] = __builtin_amdgcn_mfma_f32_16x16x32_bf16(aU[1].s, bU[nt].s, acc[1][nt], 0, 0, 0);
        }
        asm volatile("s_waitcnt lgkmcnt(0)" ::: "memory");
        __builtin_amdgcn_s_barrier();
        asm volatile("" ::: "memory");
    }
    {
        int kf = 192 + quad * 8;
        U4S8 bU[8];
        #pragma unroll
        for (int nt = 0; nt < 8; nt++)
            bU[nt].u = *(const uint4*)&wt[(long)(nt * 16 + m16) * 224 + kf];
        U4S8 aU[2];
        #pragma unroll
        for (int mt = 0; mt < 2; mt++) {
            uint4 o = {0u, 0u, 0u, 0u};
            if (kf + 8 <= 200) {
                const float* p = &xv[(row0g + wave * 32 + mt * 16 + m16) * 200 + kf];
                float4 v0 = *(const float4*)p;
                float4 v1 = *(const float4*)(p + 4);
                o.x = packbf(v0.x, v0.y); o.y = packbf(v0.z, v0.w);
                o.z = packbf(v1.x, v1.y); o.w = packbf(v1.z, v1.w);
            }
            aU[mt].u = o;
        }
        #pragma unroll
        for (int nt = 0; nt < 8; nt++) {
            acc[0][nt] = __builtin_amdgcn_mfma_f32_16x16x32_bf16(aU[0].s, bU[nt].s, acc[0][nt], 0, 0, 0);
            acc[1][nt] = __builtin_amdgcn_mfma_f32_16x16x32_bf16(aU[1].s, bU[nt].s, acc[1][nt], 0, 0, 0);
        }
    }

    unsigned short* tile = (unsigned short*)pool;
    #pragma unroll
    for (int nt = 0; nt < 8; nt++) {
        int col = nt * 16 + m16;
        float bv = bias[col];
        #pragma unroll
        for (int mt = 0; mt < 2; mt++) {
            int lrb = wave * 32 + mt * 16 + quad * 4;
            #pragma unroll
            for (int i = 0; i < 4; i++) {
                int lr = lrb + i;
                tile[lr * 128 + (col ^ ((lr & 14) << 2))] = f2bf(acc[mt][nt][i] + bv);
            }
        }
    }
    __syncthreads();
    #pragma unroll
    for (int rnd = 0; rnd < 8; rnd++) {
        int row = rnd * 16 + (tid >> 4), ch = tid & 15;
        uint4 v = *(const uint4*)&tile[row * 128 + ((ch * 8) ^ ((row & 14) << 2))];
        *(uint4*)&yrow[(row0g + row) * 128 + ch * 8] = v;
    }
    int r0 = blockIdx.x * 128;
    int bt0 = r0 / 200, n0 = r0 - bt0 * 200;
    int len0 = 200 - n0; if (len0 > 128) len0 = 128;
    int c = tid & 127, h = tid >> 7;
    #pragma unroll
    for (int u = 0; u < 8; u++) {
        int rl = h * 64 + u * 8;
        unsigned short e[8];
        #pragma unroll
        for (int j = 0; j < 8; j++)
            e[j] = tile[(rl + j) * 128 + (c ^ (((rl + j) & 14) << 2))];
        uint4 o;
        o.x = (unsigned)e[0] | ((unsigned)e[1] << 16);
        o.y = (unsigned)e[2] | ((unsigned)e[3] << 16);
        o.z = (unsigned)e[4] | ((unsigned)e[5] << 16);
        o.w = (unsigned)e[6] | ((unsigned)e[7] << 16);
        int bt, n;
        if (rl < len0) { bt = bt0; n = n0 + rl; } else { bt = bt0 + 1; n = rl - len0; }
        *(uint4*)&zt[((long)bt * 128 + c) * 224 + n] = o;
    }
    if (n0 >= 72) {
        uint4 z = {0u, 0u, 0u, 0u};
        for (int idx = tid; idx < 384; idx += 256) {
            int c2 = idx & 127, u2 = idx >> 7;
            *(uint4*)&zt[((long)bt0 * 128 + c2) * 224 + 200 + u2 * 8] = z;
        }
    }
}

// ============================================================================
// maskfused v2 (stage-all): y2 = (M@h3 + eps*h3) @ w1 + b1. Unchanged from R8.
__global__ __launch_bounds__(256) void maskfused_kernel(
        const unsigned* __restrict__ msk, const unsigned short* __restrict__ zt,
        const unsigned short* __restrict__ h3, const unsigned short* __restrict__ w1t,
        const float* __restrict__ geps, int l, const float* __restrict__ b1,
        unsigned short* __restrict__ y, float* __restrict__ statsOut) {
    __shared__ unsigned char pool[65536];
    __shared__ unsigned sbits[128 * 7];
    int tid = threadIdx.x;
    int bt = blockIdx.x & 511, half = blockIdx.x >> 9;
    int row0 = half * 128;
    int wave = tid >> 6, lane = tid & 63, quad = lane >> 4, m16 = lane & 15;
    const char* ztb = (const char*)(zt + (long)bt * 128 * 224);

    {
        int r0 = tid >> 2;
        int q0 = (tid & 3) ^ ((r0 >> 1) & 3);
        int r1 = 64 + (tid >> 2);
        int q1 = (tid & 3) ^ ((r1 >> 1) & 3);
        #pragma unroll
        for (int kc = 0; kc < 7; kc++) {
            char* dst = (char*)pool + kc * 8192;
            GLL(ztb + r0 * 448 + kc * 64 + q0 * 16, dst + wave * 1024);
            GLL(ztb + r1 * 448 + kc * 64 + q1 * 16, dst + 4096 + wave * 1024);
        }
    }
    for (int idx = tid; idx < 896; idx += 256) {
        int gr = row0 + idx / 7;
        sbits[idx] = (gr < N_) ? msk[(long)bt * 1400 + gr * 7 + (idx % 7)] : 0u;
    }
    unsigned ONEu = 0x3F80u;

    f32x4v acc[2][8];
    #pragma unroll
    for (int i = 0; i < 2; i++)
        #pragma unroll
        for (int j = 0; j < 8; j++) acc[i][j] = (f32x4v){0.f, 0.f, 0.f, 0.f};

    __syncthreads();

    #pragma unroll 1
    for (int kc = 0; kc < 7; kc++) {
        const char* sb = (const char*)pool + kc * 8192;
        U4S8 bU[8];
        #pragma unroll
        for (int nt = 0; nt < 8; nt++) {
            int r = nt * 16 + m16;
            int q = quad ^ ((r >> 1) & 3);
            bU[nt].u = *(const uint4*)(sb + r * 64 + q * 16);
        }
        U4S8 aU[2];
        #pragma unroll
        for (int mt = 0; mt < 2; mt++) {
            int lr = wave * 32 + mt * 16 + m16;
            unsigned bits = (sbits[lr * 7 + kc] >> (quad * 8)) & 0xFFu;
            unsigned o[4];
            #pragma unroll
            for (int p = 0; p < 4; p++) {
                unsigned lo = ((bits >> (2 * p)) & 1u) ? ONEu : 0u;
                unsigned hi = ((bits >> (2 * p + 1)) & 1u) ? ONEu : 0u;
                o[p] = lo | (hi << 16);
            }
            aU[mt].u = make_uint4(o[0], o[1], o[2], o[3]);
        }
        #pragma unroll
        for (int nt = 0; nt < 8; nt++) {
            acc[0][nt] = __builtin_amdgcn_mfma_f32_16x16x32_bf16(aU[0].s, bU[nt].s, acc[0][nt], 0, 0, 0);
            acc[1][nt] = __builtin_amdgcn_mfma_f32_16x16x32_bf16(aU[1].s, bU[nt].s, acc[1][nt], 0, 0, 0);
        }
    }
    __syncthreads();

    unsigned short* magg = (unsigned short*)pool;
    unsigned short* trans = (unsigned short*)(pool + 32768);
    #pragma unroll
    for (int nt = 0; nt < 8; nt++) {
        int col = nt * 16 + m16;
        #pragma unroll
        for (int mt = 0; mt < 2; mt++) {
            int lrb = wave * 32 + mt * 16 + quad * 4;
            #pragma unroll
            for (int i = 0; i < 4; i++) {
                int lr = lrb + i;
                magg[lr * 128 + (col ^ ((lr & 6) << 2))] = f2bf(acc[mt][nt][i]);
            }
        }
    }
    __syncthreads();

    float eps = geps[l];
    f32x4v acc2[2][8];
    #pragma unroll
    for (int i = 0; i < 2; i++)
        #pragma unroll
        for (int j = 0; j < 8; j++) acc2[i][j] = (f32x4v){0.f, 0.f, 0.f, 0.f};

    #pragma unroll 1
    for (int ks = 0; ks < 4; ks++) {
        int kf = ks * 32 + quad * 8;
        U4S8 bU[8];
        #pragma unroll
        for (int nt = 0; nt < 8; nt++)
            bU[nt].u = *(const uint4*)&w1t[(long)(nt * 16 + m16) * 128 + kf];
        U4S8 aU[2];
        #pragma unroll
        for (int mt = 0; mt < 2; mt++) {
            int r = wave * 32 + mt * 16 + m16;
            uint4 mu = *(const uint4*)&magg[r * 128 + (kf ^ ((r & 6) << 2))];
            int gr = row0 + r;
            uint4 hu = {0u, 0u, 0u, 0u};
            if (gr < N_) hu = *(const uint4*)&h3[((long)bt * N_ + gr) * 128 + kf];
            float f0 = bflo(mu.x) + eps * bflo(hu.x);
            float f1 = bfhi(mu.x) + eps * bfhi(hu.x);
            float f2 = bflo(mu.y) + eps * bflo(hu.y);
            float f3 = bfhi(mu.y) + eps * bfhi(hu.y);
            float f4 = bflo(mu.z) + eps * bflo(hu.z);
            float f5 = bfhi(mu.z) + eps * bfhi(hu.z);
            float f6 = bflo(mu.w) + eps * bflo(hu.w);
            float f7 = bfhi(mu.w) + eps * bfhi(hu.w);
            uint4 o;
            o.x = packbf(f0, f1); o.y = packbf(f2, f3);
            o.z = packbf(f4, f5); o.w = packbf(f6, f7);
            aU[mt].u = o;
        }
        #pragma unroll
        for (int nt = 0; nt < 8; nt++) {
            acc2[0][nt] = __builtin_amdgcn_mfma_f32_16x16x32_bf16(aU[0].s, bU[nt].s, acc2[0][nt], 0, 0, 0);
            acc2[1][nt] = __builtin_amdgcn_mfma_f32_16x16x32_bf16(aU[1].s, bU[nt].s, acc2[1][nt], 0, 0, 0);
        }
    }

    float sAcc[8], qAcc[8];
    #pragma unroll
    for (int nt = 0; nt < 8; nt++) {
        int col = nt * 16 + m16;
        float bv = b1[col];
        float s = 0.f, q = 0.f;
        #pragma unroll
        for (int mt = 0; mt < 2; mt++) {
            int lrb = wave * 32 + mt * 16 + quad * 4;
            #pragma unroll
            for (int i = 0; i < 4; i++) {
                int lr = lrb + i;
                float v = acc2[mt][nt][i] + bv;
                trans[lr * 128 + (col ^ ((lr & 6) << 2))] = f2bf(v);
                if (row0 + lr < N_) { s += v; q += v * v; }
            }
        }
        sAcc[nt] = s; qAcc[nt] = q;
    }
    __syncthreads();
    #pragma unroll
    for (int rnd = 0; rnd < 8; rnd++) {
        int row = rnd * 16 + (tid >> 4), ch = tid & 15;
        int gr = row0 + row;
        uint4 v = *(const uint4*)&trans[row * 128 + ((ch * 8) ^ ((row & 6) << 2))];
        if (gr < N_)
            *(uint4*)&y[((long)bt * N_ + gr) * 128 + ch * 8] = v;
    }
    __syncthreads();
    float* redS = (float*)(pool + 32768);
    float* redQ = redS + 2048;
    #pragma unroll
    for (int nt = 0; nt < 8; nt++) {
        int col = nt * 16 + m16;
        redS[col * 16 + wave * 4 + quad] = sAcc[nt];
        redQ[col * 16 + wave * 4 + quad] = qAcc[nt];
    }
    __syncthreads();
    if (tid < 128) {
        float s = 0.f, q = 0.f;
        #pragma unroll
        for (int j = 0; j < 16; j++) { s += redS[tid * 16 + j]; q += redQ[tid * 16 + j]; }
        atomicAdd(&statsOut[tid], s);
        atomicAdd(&statsOut[128 + tid], q);
    }
}

// ============================================================================
// xrE2: BOTH layers in one dispatch (1024 blocks: l = bid>>9, tb = bid&511).
__global__ __launch_bounds__(256) void xrE2_kernel(
        const unsigned short* __restrict__ raw0, const unsigned short* __restrict__ raw1,
        const float* __restrict__ SBUF,
        const float* __restrict__ gall, const float* __restrict__ ball,
        const float* __restrict__ swall, const float* __restrict__ sball,
        float* __restrict__ E0, float* __restrict__ E1, float* __restrict__ statBase) {
    __shared__ float red[256];
    __shared__ float xrrow[128];
    int l = blockIdx.x >> 9, tb = blockIdx.x & 511;
    const unsigned short* raw = l ? raw1 : raw0;
    const float* stats = SBUF + l * 768 + 256;     // SB_l
    const float* g = gall + l * C_;
    const float* b = ball + l * C_;
    const float* sw = swall + l * C_ * C_;
    const float* sb = sball + l * C_;
    float* E = l ? E1 : E0;
    float* statE = (float*)statBase + l * 768 + 512;   // SE_l
    int tid = threadIdx.x, c = tid & 127, hf = tid >> 7;
    int t = tb / B_, bb = tb % B_;
    const unsigned short* base = raw + ((long)bb * T_ + t) * N_ * C_;
    float m = stats[c] * (1.f / (float)RB_);
    float var = fmaxf(stats[128 + c] * (1.f / (float)RB_) - m * m, 0.f);
    float sc = g[c] / sqrtf(var + 1e-5f);
    float sh = b[c] - m * sc;
    float s = 0.f;
    for (int n = hf * 100; n < hf * 100 + 100; n++)
        s += fmaxf(fmaf(bf2f(base[n * C_ + c]), sc, sh), 0.f);
    red[tid] = s;
    __syncthreads();
    if (hf == 0) xrrow[c] = (red[c] + red[c + 128]) * (1.f / 200.f);
    __syncthreads();
    float acc = 0.f;
    for (int k = hf * 64; k < hf * 64 + 64; k++)
        acc = fmaf(xrrow[k], sw[k * C_ + c], acc);
    red[tid] = acc;
    __syncthreads();
    if (hf == 0) {
        float v = red[c] + red[c + 128] + sb[c];
        E[(long)tb * C_ + c] = v;
        atomicAdd(&statE[c], v);
        atomicAdd(&statE[C_ + c], v * v);
    }
}

// ============================================================================
// ga2: BOTH layers (256 blocks: l = bid>>7, sub = bid&127 -> 4 rows each).
__global__ __launch_bounds__(256) void ga2_kernel(
        const float* __restrict__ E0f, const float* __restrict__ E1f,
        const float* __restrict__ SBUF,
        const float* __restrict__ sgall, const float* __restrict__ sball,
        const float* __restrict__ awall, const float* __restrict__ aball,
        float* __restrict__ GA0, float* __restrict__ GA1,
        float* __restrict__ node_out) {
    __shared__ float sx[4 * C_];
    __shared__ float bnS[C_], bnB[C_];
    int l = blockIdx.x >> 7, sub = blockIdx.x & 127;
    const float* eRaw = l ? E1f : E0f;
    const float* stats = SBUF + l * 768 + 512;     // SE_l
    const float* sg = sgall + l * C_;
    const float* sb = sball + l * C_;
    const float* aw = awall + l * C_ * N_;
    const float* ab = aball + l * N_;
    float* ga = l ? GA1 : GA0;
    int tid = threadIdx.x;
    if (tid < C_) {
        float m = stats[tid] * (1.f / (float)BT_);
        float var = fmaxf(stats[C_ + tid] * (1.f / (float)BT_) - m * m, 0.f);
        float inv = 1.f / sqrtf(var + 1e-5f);
        float sc = inv * sg[tid];
        bnS[tid] = sc;
        bnB[tid] = sb[tid] - m * sc;
    }
    __syncthreads();
    long r0 = (long)sub * 4;
    for (int idx = tid; idx < 4 * C_; idx += 256) {
        int col = idx & (C_ - 1);
        float v = eRaw[r0 * C_ + idx] * bnS[col] + bnB[col];
        sx[idx] = 0.5f * v * (1.f + erff(v * 0.70710678118654752f));
    }
    __syncthreads();
    int c = tid;
    if (c < N_) {
        float acc[4] = {0.f, 0.f, 0.f, 0.f};
        for (int k = 0; k < C_; k++) {
            float wv = aw[k * N_ + c];
            #pragma unroll
            for (int i = 0; i < 4; i++) acc[i] = fmaf(sx[i * C_ + k], wv, acc[i]);
        }
        float bv = ab[c];
        for (int i = 0; i < 4; i++) {
            int tb = (int)r0 + i;
            int t = tb / B_, b = tb % B_;
            float v = 1.f / (1.f + expf(-(acc[i] + bv)));
            ga[(long)tb * N_ + c] = v;
            node_out[(((long)b * L_ + l) * T_ + t) * N_ + c] = v;
        }
    }
}

// ============================================================================
// hrQKV2: BOTH layers (1024 blocks).
__global__ __launch_bounds__(256) void hrQKV2_kernel(
        const unsigned short* __restrict__ raw0, const unsigned short* __restrict__ raw1,
        const float* __restrict__ SBUF,
        const float* __restrict__ gall, const float* __restrict__ ball,
        const float* __restrict__ GA0, const float* __restrict__ GA1,
        const float* __restrict__ wqall, const float* __restrict__ bqall,
        float* __restrict__ QKV0, float* __restrict__ QKV1) {
    __shared__ float sga[N_];
    __shared__ float red[256];
    __shared__ float hrrow[128];
    int l = blockIdx.x >> 9, tb = blockIdx.x & 511;
    const unsigned short* raw = l ? raw1 : raw0;
    const float* stats = SBUF + l * 768 + 256;
    const float* g = gall + l * C_;
    const float* b = ball + l * C_;
    const float* ga = l ? GA1 : GA0;
    const float* wq = wqall + (long)l * C_ * 3 * C_;
    const float* bq = bqall + l * 3 * C_;
    float* qkv = l ? QKV1 : QKV0;
    int tid = threadIdx.x, c = tid & 127, hf = tid >> 7;
    int t = tb / B_, bb = tb % B_;
    const unsigned short* base = raw + ((long)bb * T_ + t) * N_ * C_;
    for (int i = tid; i < N_; i += 256) sga[i] = ga[(long)tb * N_ + i];
    __syncthreads();
    float m = stats[c] * (1.f / (float)RB_);
    float var = fmaxf(stats[128 + c] * (1.f / (float)RB_) - m * m, 0.f);
    float sc = g[c] / sqrtf(var + 1e-5f);
    float sh = b[c] - m * sc;
    float s = 0.f;
    for (int n = hf * 100; n < hf * 100 + 100; n++)
        s = fmaf(fmaxf(fmaf(bf2f(base[n * C_ + c]), sc, sh), 0.f), sga[n], s);
    red[tid] = s;
    __syncthreads();
    if (hf == 0) hrrow[c] = (red[c] + red[c + 128]) * (1.f / 200.f);
    __syncthreads();
    for (int out = tid; out < 384; out += 256) {
        float acc = 0.f;
        for (int k = 0; k < C_; k++)
            acc = fmaf(hrrow[k], wq[k * 384 + out], acc);
        qkv[(long)tb * 384 + out] = acc + bq[out];
    }
}

// ============================================================================
// attnln2: BOTH layers (1024 blocks, 128 threads).
__global__ __launch_bounds__(128) void attnln2_kernel(
        const float* __restrict__ QKV0, const float* __restrict__ QKV1,
        const float* __restrict__ woall, const float* __restrict__ boall,
        const float* __restrict__ gall, const float* __restrict__ ball,
        float* __restrict__ time_out, float* __restrict__ X10, float* __restrict__ X11) {
    __shared__ float q[C_];
    __shared__ float sa[T_];
    __shared__ float av[C_];
    __shared__ float red[C_];
    int l = blockIdx.x >> 9, tb = blockIdx.x & 511;
    const float* qkv = l ? QKV1 : QKV0;
    const float* wo = woall + (long)l * C_ * C_;
    const float* bo = boall + l * C_;
    const float* g = gall + l * C_;
    const float* bb = ball + l * C_;
    float* x1 = l ? X11 : X10;
    int tid = threadIdx.x;
    int t = tb / B_, b = tb % B_;
    q[tid] = qkv[((long)t * B_ + b) * 384 + tid];
    __syncthreads();
    if (tid < 64) {
        const float* krow = qkv + ((long)tid * B_ + b) * 384 + C_;
        float s = 0.f;
        for (int c = 0; c < C_; c++) s = fmaf(q[c], krow[c], s);
        s *= 0.08838834764831843f;
        float mx = s;
        #pragma unroll
        for (int off = 32; off; off >>= 1) mx = fmaxf(mx, __shfl_xor(mx, off));
        float e = expf(s - mx), sum = e;
        #pragma unroll
        for (int off = 32; off; off >>= 1) sum += __shfl_xor(sum, off);
        float p = e / sum;
        sa[tid] = p;
        time_out[(((long)b * L_ + l) * T_ + t) * T_ + tid] = p;
    }
    __syncthreads();
    float s2 = 0.f;
    for (int sp = 0; sp < T_; sp++)
        s2 = fmaf(sa[sp], qkv[((long)sp * B_ + b) * 384 + 256 + tid], s2);
    av[tid] = s2;
    __syncthreads();
    float a0 = 0.f;
    for (int k = 0; k < C_; k++) a0 = fmaf(av[k], wo[k * C_ + tid], a0);
    float v = a0 + bo[tid];
    red[tid] = v; __syncthreads();
    for (int off = 64; off; off >>= 1) { if (tid < off) red[tid] += red[tid + off]; __syncthreads(); }
    float m = red[0] * (1.f / C_); __syncthreads();
    float d = v - m;
    red[tid] = d * d; __syncthreads();
    for (int off = 64; off; off >>= 1) { if (tid < off) red[tid] += red[tid + off]; __syncthreads(); }
    float var = red[0] * (1.f / C_);
    x1[((long)t * B_ + b) * C_ + tid] = d * (1.f / sqrtf(var + 1e-5f)) * g[tid] + bb[tid];
}

// ============================================================================
// ffn2: BOTH layers (512 blocks: l = bid>>8, 2 rows each); LAT atomicAdd.
__global__ __launch_bounds__(256) void ffn2_kernel(
        const float* __restrict__ X10, const float* __restrict__ X11,
        const float* __restrict__ w1all, const float* __restrict__ b1all,
        const float* __restrict__ w2all, const float* __restrict__ b2all,
        const float* __restrict__ gall, const float* __restrict__ ball,
        float* __restrict__ LAT) {
    __shared__ float sx[2 * C_];
    __shared__ float mid[2 * 256];
    __shared__ float red[C_];
    int l = blockIdx.x >> 8, sub = blockIdx.x & 255;
    const float* x1 = l ? X11 : X10;
    const float* w1 = w1all + (long)l * C_ * 2 * C_;
    const float* b1 = b1all + l * 2 * C_;
    const float* w2 = w2all + (long)l * 2 * C_ * C_;
    const float* b2 = b2all + l * C_;
    const float* g = gall + l * C_;
    const float* bb = ball + l * C_;
    float* lat = LAT + l * B_ * C_;
    int tid = threadIdx.x;
    long r0 = (long)sub * 2;
    sx[tid] = x1[r0 * C_ + tid];
    __syncthreads();
    float a0 = 0.f, a1 = 0.f;
    for (int k = 0; k < C_; k++) {
        float wv = w1[k * 256 + tid];
        a0 = fmaf(sx[k], wv, a0);
        a1 = fmaf(sx[C_ + k], wv, a1);
    }
    float bv = b1[tid];
    mid[tid]       = fmaxf(a0 + bv, 0.f);
    mid[256 + tid] = fmaxf(a1 + bv, 0.f);
    __syncthreads();
    float v[2] = {0.f, 0.f};
    if (tid < C_) {
        float c0 = 0.f, c1 = 0.f;
        for (int k = 0; k < 256; k++) {
            float wv = w2[k * C_ + tid];
            c0 = fmaf(mid[k], wv, c0);
            c1 = fmaf(mid[256 + k], wv, c1);
        }
        float bv2 = b2[tid];
        v[0] = c0 + bv2 + sx[tid];
        v[1] = c1 + bv2 + sx[C_ + tid];
    }
    #pragma unroll 1
    for (int r = 0; r < 2; r++) {
        if (tid < C_) red[tid] = v[r];
        __syncthreads();
        for (int off = 64; off; off >>= 1) { if (tid < off) red[tid] += red[tid + off]; __syncthreads(); }
        float m = red[0] * (1.f / C_); __syncthreads();
        float d = v[r] - m;
        if (tid < C_) red[tid] = d * d;
        __syncthreads();
        for (int off = 64; off; off >>= 1) { if (tid < off) red[tid] += red[tid + off]; __syncthreads(); }
        float var = red[0] * (1.f / C_); __syncthreads();
        if (tid < C_) {
            float outv = d * (1.f / sqrtf(var + 1e-5f)) * g[tid] + bb[tid];
            int b = (int)((r0 + r) % B_);
            atomicAdd(&lat[b * C_ + tid], outv);
        }
    }
}

// ---------------- logit + feat_fMRI
__global__ void final_kernel(const float* __restrict__ lat, const float* __restrict__ cls_w,
                             const float* __restrict__ cls_b, float* __restrict__ out) {
    int idx = blockIdx.x * blockDim.x + threadIdx.x;
    if (idx < B_ * NC_) {
        int b = idx / NC_, nc = idx % NC_;
        float s = 0.f;
        for (int l = 0; l < L_; l++) {
            float acc = 0.f;
            for (int c = 0; c < C_; c++)
                acc = fmaf(lat[l * B_ * C_ + b * C_ + c], cls_w[l * C_ * NC_ + c * NC_ + nc], acc);
            s += acc + cls_b[l * NC_ + nc];
        }
        out[idx] = s;
    } else if (idx < B_ * NC_ + B_ * C_) {
        int j = idx - B_ * NC_;
        out[idx] = 0.5f * (lat[j] + lat[B_ * C_ + j]);
    }
}

// ---------------- feat_sMRI = bn(trad @ smri_w + smri_b) over batch of 8
__global__ void smri_kernel(const float* __restrict__ trad, const float* __restrict__ w,
                            const float* __restrict__ bias, const float* __restrict__ g,
                            const float* __restrict__ bb, float* __restrict__ out) {
    int c = threadIdx.x;
    float y[B_];
    for (int b = 0; b < B_; b++) {
        float s = bias[c];
        for (int k = 0; k < S_; k++) s = fmaf(trad[b * S_ + k], w[k * C_ + c], s);
        y[b] = s;
    }
    float m = 0.f;
    for (int b = 0; b < B_; b++) m += y[b];
    m *= (1.f / B_);
    float var = 0.f;
    for (int b = 0; b < B_; b++) { float d = y[b] - m; var += d * d; }
    var *= (1.f / B_);
    float inv = 1.f / sqrtf(var + 1e-5f);
    for (int b = 0; b < B_; b++) out[b * C_ + c] = (y[b] - m) * inv * g[c] + bb[c];
}

// ============================================================================
extern "C" void kernel_launch(void* const* d_in, const int* in_sizes, int n_in,
                              void* d_out, int out_size, void* d_ws, size_t ws_size,
                              hipStream_t stream) {
    const float* fv       = (const float*)d_in[0];
    const float* fa       = (const float*)d_in[1];
    const float* trad     = (const float*)d_in[2];
    const float* w_init   = (const float*)d_in[6];
    const float* b_init   = (const float*)d_in[7];
    const float* gin_eps  = (const float*)d_in[8];
    const float* gin_w1   = (const float*)d_in[9];
    const float* gin_b1   = (const float*)d_in[10];
    const float* gbn1g    = (const float*)d_in[11];
    const float* gbn1b    = (const float*)d_in[12];
    const float* gin_w2   = (const float*)d_in[13];
    const float* gin_b2   = (const float*)d_in[14];
    const float* gbn2g    = (const float*)d_in[15];
    const float* gbn2b    = (const float*)d_in[16];
    const float* sero_w   = (const float*)d_in[17];
    const float* sero_b   = (const float*)d_in[18];
    const float* sbng     = (const float*)d_in[19];
    const float* sbnb     = (const float*)d_in[20];
    const float* sero_aw  = (const float*)d_in[21];
    const float* sero_ab  = (const float*)d_in[22];
    const float* wqkv     = (const float*)d_in[23];
    const float* bqkv     = (const float*)d_in[24];
    const float* wo       = (const float*)d_in[25];
    const float* bo       = (const float*)d_in[26];
    const float* ln1g     = (const float*)d_in[27];
    const float* ln1b     = (const float*)d_in[28];
    const float* ln2g     = (const float*)d_in[29];
    const float* ln2b     = (const float*)d_in[30];
    const float* tw1      = (const float*)d_in[31];
    const float* tb1      = (const float*)d_in[32];
    const float* tw2      = (const float*)d_in[33];
    const float* tb2      = (const float*)d_in[34];
    const float* cls_w    = (const float*)d_in[35];
    const float* cls_b    = (const float*)d_in[36];
    const float* smri_w   = (const float*)d_in[37];
    const float* smri_b   = (const float*)d_in[38];
    const float* smri_g   = (const float*)d_in[39];
    const float* smri_bb  = (const float*)d_in[40];

    float* out = (float*)d_out;

    // workspace layout
    const long SZ_BIG = (long)RB_ * C_;            // 13,107,200 elements
    unsigned short* H3b  = (unsigned short*)d_ws;  // h3 row-major bf16
    unsigned short* Y1b0 = H3b + SZ_BIG;           // layer-0 Y1raw
    unsigned short* Y2b  = Y1b0 + SZ_BIG;          // y2 (shared, sequential use)
    unsigned short* ZTb  = Y2b + SZ_BIG;           // h3^T; ALIASED as Y1b1 after mf(1)
    unsigned short* Y1b1 = ZTb;                    // layer-1 Y1raw (alias: ZTb dead after mf(1))
    float* fbase = (float*)(ZTb + (long)BT_ * 128 * 224);
    float* THR  = fbase;                  // 512
    float* SBUF = THR + 512;              // 6 x 256 stat buffers (SA,SB,SE per layer)
    float* LAT  = SBUF + 1536;            // 2 x 8 x 128
    float* E0   = LAT + 2048;             // 512*128
    float* GA0  = E0 + BT_ * C_;          // 512*200
    float* QKV0 = GA0 + BT_ * N_;         // 512*384
    float* X10  = QKV0 + BT_ * 3 * C_;    // 512*128
    unsigned short* WT0 = (unsigned short*)(X10 + BT_ * C_);      // w_init^T: 128 x 224
    unsigned short* WT1 = WT0 + 128 * 224;                        // gin_w1^T: 2 x (128x128)
    unsigned short* WT2 = WT1 + 2 * 128 * 128;                    // gin_w2^T: 2 x (128x128)
    unsigned* MSK = (unsigned*)(WT2 + 2 * 128 * 128);             // 512x200x7 words (2.87MB)
    // layer-1 tail floats ALIAS the MSK region (dead after mf(1)); 1.72MB <= 2.87MB
    float* E1   = (float*)MSK;
    float* GA1  = E1 + BT_ * C_;
    float* QKV1 = GA1 + BT_ * N_;
    float* X11  = QKV1 + BT_ * 3 * C_;

    // output layout (floats)
    float* OUT_LOGIT = out;            // 16 logit + 1024 feat_fMRI
    float* OUT_FEATS = out + 1040;     // 1024 (feat_sMRI)
    float* OUT_NODE  = out + 2064;     // 204800
    float* OUT_TIME  = out + 206864;   // 65536

    // ---- one batched weight cvt + ONE memset for all stats + LAT
    wtcvt5_kernel<<<640, 64, 0, stream>>>(w_init, gin_w1, gin_w2, WT0, WT1, WT2);
    hipMemsetAsync(SBUF, 0, (1536 + 2048) * sizeof(float), stream);

    // h3 = fv @ w_init + b_init, dual output (row-major + transposed), ONCE
    h3gemmT_kernel<<<RB_ / 128, 256, 0, stream>>>(fv, WT0, b_init, H3b, ZTb);
    thr_kernel<<<BT_, 1024, 0, stream>>>(fa, THR, MSK);

    // ---- big GEMMs: per-layer sequential (Y2b reused; ZTb->Y1b1 alias safe
    // because stream order guarantees mf(1) finishes before bg(1) writes)
    maskfused_kernel<<<BT_ * 2, 256, 0, stream>>>(MSK, ZTb, H3b, WT1,
        gin_eps, 0, gin_b1, Y2b, SBUF);
    bngemm_kernel<<<RB_ / 128, 256, 0, stream>>>(
        Y2b, WT2, gin_b2, SBUF, gbn1g, gbn1b, Y1b0, SBUF + 256);
    maskfused_kernel<<<BT_ * 2, 256, 0, stream>>>(MSK, ZTb, H3b, WT1 + 128 * 128,
        gin_eps, 1, gin_b1 + C_, Y2b, SBUF + 768);
    bngemm_kernel<<<RB_ / 128, 256, 0, stream>>>(
        Y2b, WT2 + 128 * 128, gin_b2 + C_, SBUF + 768, gbn1g + C_, gbn1b + C_,
        Y1b1, SBUF + 768 + 256);

    // ---- tail: BOTH layers merged per stage (half the chain, 2x parallelism)
    xrE2_kernel<<<2 * BT_, 256, 0, stream>>>(Y1b0, Y1b1, SBUF, gbn2g, gbn2b,
        sero_w, sero_b, E0, E1, SBUF);
    ga2_kernel<<<2 * (BT_ / 4), 256, 0, stream>>>(E0, E1, SBUF, sbng, sbnb,
        sero_aw, sero_ab, GA0, GA1, OUT_NODE);
    hrQKV2_kernel<<<2 * BT_, 256, 0, stream>>>(Y1b0, Y1b1, SBUF, gbn2g, gbn2b,
        GA0, GA1, wqkv, bqkv, QKV0, QKV1);
    attnln2_kernel<<<2 * BT_, 128, 0, stream>>>(QKV0, QKV1, wo, bo, ln1g, ln1b,
        OUT_TIME, X10, X11);
    ffn2_kernel<<<2 * (BT_ / 2), 256, 0, stream>>>(X10, X11, tw1, tb1, tw2, tb2,
        ln2g, ln2b, LAT);

    final_kernel<<<5, 256, 0, stream>>>(LAT, cls_w, cls_b, OUT_LOGIT);
    smri_kernel<<<1, 128, 0, stream>>>(trad, smri_w, smri_b, smri_g, smri_bb, OUT_FEATS);
}